// Round 8
// baseline (458.462 us; speedup 1.0000x reference)
//
#include <hip/hip_runtime.h>
#include <math.h>

#define NUM_TREES 4096
#define TOTAL_NODES 1048576
#define DCOL 256
#define DPW 64             // float4 units per row (D=256/4)
#define SLICE 128          // rows per wave: 8192 waves * 128 = TOTAL_NODES
#define NWAVES 8192
#define PROBE_THREADS (2048 * 256)   // 524288 threads -> 128 front steps

typedef float f4v __attribute__((ext_vector_type(4)));

static __device__ __forceinline__ f4v vmax4(f4v a, f4v b) {
    f4v r;
    r.x = fmaxf(a.x, b.x);
    r.y = fmaxf(a.y, b.y);
    r.z = fmaxf(a.z, b.z);
    r.w = fmaxf(a.w, b.w);
    return r;
}

// float atomic max via CAS loop (proven R5)
static __device__ __forceinline__ void atomicFmax(float* addr, float val) {
    unsigned* u = (unsigned*)addr;
    unsigned old = *u;
    while (__uint_as_float(old) < val) {
        unsigned assumed = old;
        old = atomicCAS(u, assumed, __float_as_uint(val));
        if (old == assumed) break;
    }
}

// stream rows [lo,hi), split at tree boundaries, commit each segment's max
static __device__ __forceinline__ void process_range(const f4v* __restrict__ src,
                                                     const int* __restrict__ row_off,
                                                     float* __restrict__ out,
                                                     int lane, int lo, int hi) {
    if (lo >= hi) return;
    int l = 0, h = NUM_TREES;
    while (h - l > 1) {
        int mid = (l + h) >> 1;
        if (row_off[mid] <= lo) l = mid; else h = mid;
    }
    int t = l;
    const float NEG = -INFINITY;
    long idx = (long)lo * DPW + lane;
    while (lo < hi) {
        int e = min(hi, row_off[t + 1]);
        if (e <= lo) break;
        f4v acc = { NEG, NEG, NEG, NEG };
        int r = lo;
        for (; r + 4 <= e; r += 4, idx += 4 * DPW) {
            f4v x = src[idx];
            f4v y = src[idx + DPW];
            f4v z = src[idx + 2 * DPW];
            f4v w = src[idx + 3 * DPW];
            acc = vmax4(acc, vmax4(vmax4(x, y), vmax4(z, w)));
        }
        for (; r < e; ++r, idx += DPW) acc = vmax4(acc, src[idx]);
        float* dst = out + (long)t * DCOL + lane * 4;
        atomicFmax(dst + 0, acc.x);
        atomicFmax(dst + 1, acc.y);
        atomicFmax(dst + 2, acc.z);
        atomicFmax(dst + 3, acc.w);
        lo = e;
        ++t;
    }
}

// ---------------- Kernel 1 (fused): block 0 = prefix sum; blocks 1..1024 init out ----
__global__ void TreeAgg_prep_init(const void* __restrict__ sizes_raw,
                                  int* __restrict__ row_off,
                                  float* __restrict__ out) {
    if (blockIdx.x == 0) {
        __shared__ int s_row[256];
        __shared__ int s_is64;
        const int t = threadIdx.x;
        const int base = t * 16;
        const int* s32 = (const int*)sizes_raw;

        int ls[16];
        int rsum = 0;
        #pragma unroll
        for (int i = 0; i < 16; ++i) { ls[i] = s32[base + i]; rsum += ls[i]; }
        s_row[t] = rsum;
        __syncthreads();
        if (t == 0) {
            long long tot = 0;
            for (int i = 0; i < 256; ++i) tot += (long long)s_row[i];
            s_is64 = (tot != (long long)TOTAL_NODES) ? 1 : 0;
        }
        __syncthreads();
        if (s_is64) {
            const long long* s64 = (const long long*)sizes_raw;
            #pragma unroll
            for (int i = 0; i < 16; ++i) ls[i] = (int)s64[base + i];
            int rs = 0;
            #pragma unroll
            for (int i = 0; i < 16; ++i) rs += ls[i];
            s_row[t] = rs;
            __syncthreads();
        }
        if (t == 0) {
            int ra = 0;
            for (int i = 0; i < 256; ++i) { int r = s_row[i]; s_row[i] = ra; ra += r; }
            row_off[NUM_TREES] = ra;
        }
        __syncthreads();
        int ro = s_row[t];
        #pragma unroll
        for (int i = 0; i < 16; ++i) { row_off[base + i] = ro; ro += ls[i]; }
    } else {
        const int i = (blockIdx.x - 1) * blockDim.x + threadIdx.x;
        const float NEG = -INFINITY;
        ((float4*)out)[i] = make_float4(NEG, NEG, NEG, NEG);
    }
}

// ---------------- Kernel 2: R5 main, unchanged (contiguous 128-row slice per wave) ----
__global__ __launch_bounds__(256, 8)
void TreeAgg_main(const float* __restrict__ emb,
                  const int* __restrict__ row_off,
                  float* __restrict__ out) {
    const int wid  = (blockIdx.x * 256 + threadIdx.x) >> 6;
    const int lane = threadIdx.x & 63;
    const int a = wid * SLICE;
    const int b = a + SLICE;
    const f4v* __restrict__ src = (const f4v*)emb;
    process_range(src, row_off, out, lane, a, b);
}

// ---------------- Kernel 3: READ-CEILING PROBE (dense front, fill-like order) ----------
// 524288 threads sweep the 1 GiB as a contiguous 8 MB front, 128 steps.
// Output (per-thread running max) stored non-atomically to ws (visible side
// effect -> no DCE). Measures the pure coalesced READ ceiling; probe_time =
// total_dur - 238.7us.
__global__ __launch_bounds__(256, 8)
void TreeAgg_probe(const float* __restrict__ emb, float* __restrict__ ws_out) {
    const int g = blockIdx.x * 256 + threadIdx.x;
    const f4v* __restrict__ src = (const f4v*)emb;
    const float NEG = -INFINITY;
    f4v acc = { NEG, NEG, NEG, NEG };
    #pragma unroll 8
    for (int s = 0; s < 128; ++s) {
        acc = vmax4(acc, src[(long)s * PROBE_THREADS + g]);
    }
    ((f4v*)ws_out)[g] = acc;
}

extern "C" void kernel_launch(void* const* d_in, const int* in_sizes, int n_in,
                              void* d_out, int out_size, void* d_ws, size_t ws_size,
                              hipStream_t stream) {
    const float* emb   = (const float*)d_in[0];
    const void*  sizes = d_in[1];
    float*       out   = (float*)d_out;

    char* ws = (char*)d_ws;
    int*   row_off  = (int*)ws;                       // 4097 ints
    float* probe_ws = (float*)(ws + (1 << 20));       // probe sink @ +1MB (8MB)

    TreeAgg_prep_init<<<1025, 256, 0, stream>>>(sizes, row_off, out);
    TreeAgg_main<<<NWAVES * 64 / 256, 256, 0, stream>>>(emb, row_off, out);
    // measurement probe (correctness-neutral)
    TreeAgg_probe<<<2048, 256, 0, stream>>>(emb, probe_ws);
}

// Round 9
// 237.923 us; speedup vs baseline: 1.9269x; 1.9269x over previous
//
#include <hip/hip_runtime.h>
#include <math.h>

#define NUM_TREES 4096
#define TOTAL_NODES 1048576
#define DCOL 256
#define DPW 64             // float4 units per row (D=256/4)
#define SLICE 128          // rows per wave: 8192 waves * 128 = TOTAL_NODES
#define NWAVES 8192

typedef float f4v __attribute__((ext_vector_type(4)));

static __device__ __forceinline__ f4v vmax4(f4v a, f4v b) {
    f4v r;
    r.x = fmaxf(a.x, b.x);
    r.y = fmaxf(a.y, b.y);
    r.z = fmaxf(a.z, b.z);
    r.w = fmaxf(a.w, b.w);
    return r;
}

// float atomic max via CAS loop (proven R5)
static __device__ __forceinline__ void atomicFmax(float* addr, float val) {
    unsigned* u = (unsigned*)addr;
    unsigned old = *u;
    while (__uint_as_float(old) < val) {
        unsigned assumed = old;
        old = atomicCAS(u, assumed, __float_as_uint(val));
        if (old == assumed) break;
    }
}

// stream rows [lo,hi), split at tree boundaries, commit each segment's max
static __device__ __forceinline__ void process_range(const f4v* __restrict__ src,
                                                     const int* __restrict__ row_off,
                                                     float* __restrict__ out,
                                                     int lane, int lo, int hi) {
    if (lo >= hi) return;
    // largest t with row_off[t] <= lo (wave-uniform)
    int l = 0, h = NUM_TREES;
    while (h - l > 1) {
        int mid = (l + h) >> 1;
        if (row_off[mid] <= lo) l = mid; else h = mid;
    }
    int t = l;
    const float NEG = -INFINITY;
    long idx = (long)lo * DPW + lane;
    while (lo < hi) {
        int e = min(hi, row_off[t + 1]);
        if (e <= lo) break;                   // insurance vs corrupt offsets
        f4v acc = { NEG, NEG, NEG, NEG };
        int r = lo;
        for (; r + 4 <= e; r += 4, idx += 4 * DPW) {
            f4v x = src[idx];
            f4v y = src[idx + DPW];
            f4v z = src[idx + 2 * DPW];
            f4v w = src[idx + 3 * DPW];
            acc = vmax4(acc, vmax4(vmax4(x, y), vmax4(z, w)));
        }
        for (; r < e; ++r, idx += DPW) acc = vmax4(acc, src[idx]);
        float* dst = out + (long)t * DCOL + lane * 4;
        atomicFmax(dst + 0, acc.x);
        atomicFmax(dst + 1, acc.y);
        atomicFmax(dst + 2, acc.z);
        atomicFmax(dst + 3, acc.w);
        lo = e;
        ++t;
    }
}

// ---------------- Kernel 1 (fused): block 0 = prefix sum; blocks 1..1024 init out ----
// tree_sizes dtype auto-detect (int32 in practice) — proven R4-R8.
__global__ void TreeAgg_prep_init(const void* __restrict__ sizes_raw,
                                  int* __restrict__ row_off,
                                  float* __restrict__ out) {
    if (blockIdx.x == 0) {
        __shared__ int s_row[256];
        __shared__ int s_is64;
        const int t = threadIdx.x;            // each owns 16 trees
        const int base = t * 16;
        const int* s32 = (const int*)sizes_raw;

        int ls[16];
        int rsum = 0;
        #pragma unroll
        for (int i = 0; i < 16; ++i) { ls[i] = s32[base + i]; rsum += ls[i]; }
        s_row[t] = rsum;
        __syncthreads();
        if (t == 0) {
            long long tot = 0;
            for (int i = 0; i < 256; ++i) tot += (long long)s_row[i];
            s_is64 = (tot != (long long)TOTAL_NODES) ? 1 : 0;
        }
        __syncthreads();
        if (s_is64) {
            const long long* s64 = (const long long*)sizes_raw;
            #pragma unroll
            for (int i = 0; i < 16; ++i) ls[i] = (int)s64[base + i];
            int rs = 0;
            #pragma unroll
            for (int i = 0; i < 16; ++i) rs += ls[i];
            s_row[t] = rs;
            __syncthreads();
        }
        if (t == 0) {
            int ra = 0;
            for (int i = 0; i < 256; ++i) { int r = s_row[i]; s_row[i] = ra; ra += r; }
            row_off[NUM_TREES] = ra;          // == TOTAL_NODES
        }
        __syncthreads();
        int ro = s_row[t];
        #pragma unroll
        for (int i = 0; i < 16; ++i) { row_off[base + i] = ro; ro += ls[i]; }
    } else {
        const int i = (blockIdx.x - 1) * blockDim.x + threadIdx.x;   // 262144 float4
        const float NEG = -INFINITY;
        ((float4*)out)[i] = make_float4(NEG, NEG, NEG, NEG);
    }
}

// ---------------- Kernel 2: balanced streaming max (R5, proven 238.7us) ----------------
// Wave w owns rows [w*128, w*128+128): identical work per wave, split at tree
// boundaries, committed via float CAS-max. All 8192 waves co-resident (<=64 VGPR).
// Main pass runs at ~97% of the directly-measured pure-read ceiling (4.88 TB/s, R8 probe).
__global__ __launch_bounds__(256, 8)
void TreeAgg_main(const float* __restrict__ emb,
                  const int* __restrict__ row_off,
                  float* __restrict__ out) {
    const int wid  = (blockIdx.x * 256 + threadIdx.x) >> 6;   // 0..8191
    const int lane = threadIdx.x & 63;
    const int a = wid * SLICE;
    const int b = a + SLICE;
    const f4v* __restrict__ src = (const f4v*)emb;   // row r = f4v idx r*64
    process_range(src, row_off, out, lane, a, b);
}

extern "C" void kernel_launch(void* const* d_in, const int* in_sizes, int n_in,
                              void* d_out, int out_size, void* d_ws, size_t ws_size,
                              hipStream_t stream) {
    const float* emb   = (const float*)d_in[0];
    const void*  sizes = d_in[1];                 // int32 or int64, auto-detected
    float*       out   = (float*)d_out;

    int* row_off = (int*)d_ws;                    // 4097 ints

    TreeAgg_prep_init<<<1025, 256, 0, stream>>>(sizes, row_off, out);

    // main: 8192 waves, 4 waves/block -> 2048 blocks
    TreeAgg_main<<<NWAVES * 64 / 256, 256, 0, stream>>>(emb, row_off, out);
}